// Round 2
// baseline (188.161 us; speedup 1.0000x reference)
//
#include <hip/hip_runtime.h>
#include <hip/hip_bf16.h>

typedef short short8 __attribute__((ext_vector_type(8)));
typedef short short4v __attribute__((ext_vector_type(4)));
typedef float f32x4 __attribute__((ext_vector_type(4)));
typedef unsigned short ushort_t;

// ---------- bf16 helpers ----------
__device__ inline ushort_t f2bf(float f) {            // manual RNE (cold paths)
    union { float f; unsigned u; } x; x.f = f;
    unsigned r = x.u + 0x7fffu + ((x.u >> 16) & 1u);
    return (ushort_t)(r >> 16);
}
__device__ inline ushort_t f2bf_u(float x) {           // toolchain conversion (hot paths)
    union { __hip_bfloat16 h; ushort_t u; } cv;
    cv.h = __float2bfloat16(x);
    return cv.u;
}
__device__ inline float bf2f(ushort_t u) {
    union { unsigned u; float f; } cv; cv.u = ((unsigned)u) << 16; return cv.f;
}

// ---------- transpose + convert weights: Wt[j][k] = bf16(W[k][j]), K=256 rows ----------
__global__ __launch_bounds__(256) void prep_w_kernel(const float* __restrict__ w0,
                                                     const float* __restrict__ w1,
                                                     const float* __restrict__ w2,
                                                     const float* __restrict__ w3,
                                                     ushort_t* __restrict__ t0,
                                                     ushort_t* __restrict__ t1,
                                                     ushort_t* __restrict__ t2,
                                                     ushort_t* __restrict__ t3) {
    int z = blockIdx.y;
    const float* W; ushort_t* T; int J;
    if (z == 0)      { W = w0; T = t0; J = 512; }
    else if (z == 1) { W = w1; T = t1; J = 512; }
    else if (z == 2) { W = w2; T = t2; J = 256; }
    else             { W = w3; T = t3; J = 256; }
    int idx = blockIdx.x * 256 + threadIdx.x;   // idx = j*256 + k
    if (idx >= J * 256) return;
    int k = idx & 255, j = idx >> 8;
    T[idx] = f2bf(W[k * J + j]);
}

// ---------- in-projection GEMM (fused f32->bf16 convert of A) ----------
// A: x f32 [B*N=4096][256]. Bt: wt bf16 [512][256]. Outputs:
//   cols 0..255  -> rH  bf16 [B*H=16][N=2048][32]  (head-major rows)
//   cols 256..511-> vT  bf16 [B*H=16][32][N=2048]  (transposed per head)
__global__ __launch_bounds__(256) void gemm_in_kernel(
    const float* __restrict__ A0, const float* __restrict__ A1,
    const ushort_t* __restrict__ B0, const ushort_t* __restrict__ B1,
    ushort_t* __restrict__ R0, ushort_t* __restrict__ R1,
    ushort_t* __restrict__ V0, ushort_t* __restrict__ V1) {
    const float* A = blockIdx.z ? A1 : A0;
    const ushort_t* Bt = blockIdx.z ? B1 : B0;
    ushort_t* R = blockIdx.z ? R1 : R0;
    ushort_t* Vt = blockIdx.z ? V1 : V0;
    constexpr int K = 256;
    const int w = threadIdx.x >> 6, lane = threadIdx.x & 63;
    const int l16 = lane & 15, g = lane >> 4;
    const int m0 = blockIdx.x * 64 + w * 16;
    const int cb = blockIdx.y * 64;

    f32x4 acc[4] = {};
    const float* Ap = A + (size_t)(m0 + l16) * K + 8 * g;
    const ushort_t* Bp = Bt + (size_t)(cb + l16) * K + 8 * g;

    #pragma unroll
    for (int ks = 0; ks < K; ks += 32) {
        float4 af0 = *reinterpret_cast<const float4*>(Ap + ks);
        float4 af1 = *reinterpret_cast<const float4*>(Ap + ks + 4);
        short8 a;
        a[0] = (short)f2bf_u(af0.x); a[1] = (short)f2bf_u(af0.y);
        a[2] = (short)f2bf_u(af0.z); a[3] = (short)f2bf_u(af0.w);
        a[4] = (short)f2bf_u(af1.x); a[5] = (short)f2bf_u(af1.y);
        a[6] = (short)f2bf_u(af1.z); a[7] = (short)f2bf_u(af1.w);
        #pragma unroll
        for (int c = 0; c < 4; ++c) {
            short8 b = *reinterpret_cast<const short8*>(Bp + (size_t)c * 16 * K + ks);
            acc[c] = __builtin_amdgcn_mfma_f32_16x16x32_bf16(a, b, acc[c], 0, 0, 0);
        }
    }

    if (blockIdx.y < 4) {
        // r-part, head-major: rH[(b*8+h)*2048 + n][d]
        #pragma unroll
        for (int c = 0; c < 4; ++c) {
            int col = cb + c * 16 + l16;        // 0..255
            int h = col >> 5, d = col & 31;
            #pragma unroll
            for (int r = 0; r < 4; ++r) {
                int row = m0 + 4 * g + r;
                int bb = row >> 11, n = row & 2047;
                R[((size_t)(bb * 8 + h) * 2048 + n) * 32 + d] = f2bf_u(acc[c][r]);
            }
        }
    } else {
        // v-part, transposed: vT[(b*8+h)*32 + d][n], 4 consecutive n -> ushort4
        #pragma unroll
        for (int c = 0; c < 4; ++c) {
            int colp = cb - 256 + c * 16 + l16; // 0..255
            int h = colp >> 5, d = colp & 31;
            int row = m0 + 4 * g;
            int bb = row >> 11, n = row & 2047;
            ushort4 s;
            s.x = f2bf_u(acc[c][0]); s.y = f2bf_u(acc[c][1]);
            s.z = f2bf_u(acc[c][2]); s.w = f2bf_u(acc[c][3]);
            *reinterpret_cast<ushort4*>(Vt + ((size_t)(bb * 8 + h) * 32 + d) * 2048 + n) = s;
        }
    }
}

// ---------- flash attention, both directions, no LDS ----------
// rH: [16][2048][32] bf16 (Q/K rows). vT: [16][32][2048] bf16. O: [B][N][256] bf16.
__global__ __launch_bounds__(256, 4) void attn_kernel(
    const ushort_t* __restrict__ r_sed, const ushort_t* __restrict__ r_doa,
    const ushort_t* __restrict__ vT_sed, const ushort_t* __restrict__ vT_doa,
    ushort_t* __restrict__ o_sed, ushort_t* __restrict__ o_doa) {
    const int dir = blockIdx.z;
    const ushort_t* rQ = dir ? r_doa : r_sed;
    const ushort_t* rK = dir ? r_sed : r_doa;
    const ushort_t* vT = dir ? vT_sed : vT_doa;
    ushort_t* O = dir ? o_doa : o_sed;

    const int b = blockIdx.y >> 3, h = blockIdx.y & 7;
    const int w = threadIdx.x >> 6;
    const int lane = threadIdx.x & 63;
    const int l16 = lane & 15, g = lane >> 4;
    const int q_row = blockIdx.x * 64 + w * 16 + l16;
    const int bh = b * 8 + h;

    // Q fragment, pre-scaled by SCALE*log2(e)
    const float C2 = 0.17677669529663687f * 1.4426950408889634f;
    short8 qf;
    {
        short8 qr = *reinterpret_cast<const short8*>(rQ + ((size_t)bh * 2048 + q_row) * 32 + 8 * g);
        #pragma unroll
        for (int i = 0; i < 8; ++i) qf[i] = (short)f2bf(bf2f((ushort_t)qr[i]) * C2);
    }

    const ushort_t* Kb = rK + (size_t)bh * 2048 * 32 + 8 * g;
    const ushort_t* Vp0 = vT + ((size_t)bh * 32 + l16) * 2048 + 4 * g;       // d = l16
    const ushort_t* Vp1 = Vp0 + (size_t)16 * 2048;                           // d = l16+16

    float m = -1e30f, m8 = -1e30f;
    float lv[8] = {};
    f32x4 acc0 = {}, acc1 = {};

    #pragma unroll 2
    for (int kv0 = 0; kv0 < 2048; kv0 += 32) {
        const f32x4 z4 = {};
        short8 kf0 = *reinterpret_cast<const short8*>(Kb + (size_t)(kv0 + l16) * 32);
        short8 kf1 = *reinterpret_cast<const short8*>(Kb + (size_t)(kv0 + 16 + l16) * 32);
        f32x4 st0 = __builtin_amdgcn_mfma_f32_16x16x32_bf16(kf0, qf, z4, 0, 0, 0);
        f32x4 st1 = __builtin_amdgcn_mfma_f32_16x16x32_bf16(kf1, qf, z4, 0, 0, 0);

        // per-lane max (max3-friendly chains)
        float pmax = fmaxf(fmaxf(fmaxf(st0[0], st0[1]), st0[2]), st0[3]);
        pmax = fmaxf(fmaxf(fmaxf(pmax, st1[0]), st1[1]), fmaxf(st1[2], st1[3]));

        if (!__all(pmax <= m8)) {                 // deferred-max trigger (rare)
            float pm = pmax;
            pm = fmaxf(pm, __shfl_xor(pm, 16));
            pm = fmaxf(pm, __shfl_xor(pm, 32));   // row max (over g)
            float mn = fmaxf(m, pm);
            float alpha = __builtin_amdgcn_exp2f(m - mn);
            #pragma unroll
            for (int i = 0; i < 4; ++i) { acc0[i] *= alpha; acc1[i] *= alpha; }
            #pragma unroll
            for (int i = 0; i < 8; ++i) lv[i] *= alpha;
            m = mn; m8 = mn + 8.0f;
        }

        float p[8];
        #pragma unroll
        for (int i = 0; i < 4; ++i) {
            p[i]     = __builtin_amdgcn_exp2f(st0[i] - m);
            p[4 + i] = __builtin_amdgcn_exp2f(st1[i] - m);
        }
        #pragma unroll
        for (int i = 0; i < 8; ++i) lv[i] += p[i];

        short8 pf;
        #pragma unroll
        for (int i = 0; i < 8; ++i) pf[i] = (short)f2bf_u(p[i]);

        short4v v00 = *reinterpret_cast<const short4v*>(Vp0 + kv0);
        short4v v01 = *reinterpret_cast<const short4v*>(Vp0 + kv0 + 16);
        short4v v10 = *reinterpret_cast<const short4v*>(Vp1 + kv0);
        short4v v11 = *reinterpret_cast<const short4v*>(Vp1 + kv0 + 16);
        short8 vf0 = __builtin_shufflevector(v00, v01, 0, 1, 2, 3, 4, 5, 6, 7);
        short8 vf1 = __builtin_shufflevector(v10, v11, 0, 1, 2, 3, 4, 5, 6, 7);

        acc0 = __builtin_amdgcn_mfma_f32_16x16x32_bf16(vf0, pf, acc0, 0, 0, 0);
        acc1 = __builtin_amdgcn_mfma_f32_16x16x32_bf16(vf1, pf, acc1, 0, 0, 0);
    }

    float l = ((lv[0] + lv[1]) + (lv[2] + lv[3])) + ((lv[4] + lv[5]) + (lv[6] + lv[7]));
    l += __shfl_xor(l, 16);
    l += __shfl_xor(l, 32);
    const float inv = 1.0f / l;

    ushort_t* orow = O + ((size_t)b * 2048 + q_row) * 256 + h * 32;
    ushort4 o0, o1;
    o0.x = f2bf(acc0[0] * inv); o0.y = f2bf(acc0[1] * inv);
    o0.z = f2bf(acc0[2] * inv); o0.w = f2bf(acc0[3] * inv);
    o1.x = f2bf(acc1[0] * inv); o1.y = f2bf(acc1[1] * inv);
    o1.z = f2bf(acc1[2] * inv); o1.w = f2bf(acc1[3] * inv);
    *reinterpret_cast<ushort4*>(orow + 4 * g) = o0;
    *reinterpret_cast<ushort4*>(orow + 16 + 4 * g) = o1;
}

// ---------- out-projection GEMM: C[4096 x 256] = A @ Bt^T + bias, f32 out ----------
__global__ __launch_bounds__(256) void gemm_out_kernel(
    const ushort_t* __restrict__ a0, const ushort_t* __restrict__ a1,
    const ushort_t* __restrict__ b0, const ushort_t* __restrict__ b1,
    float* __restrict__ c0, float* __restrict__ c1,
    const float* __restrict__ bias0, const float* __restrict__ bias1) {
    const ushort_t* A = blockIdx.z ? a1 : a0;
    const ushort_t* Bt = blockIdx.z ? b1 : b0;
    float* C = blockIdx.z ? c1 : c0;
    const float* bias = blockIdx.z ? bias1 : bias0;
    constexpr int K = 256, N = 256;
    const int w = threadIdx.x >> 6, lane = threadIdx.x & 63;
    const int l16 = lane & 15, g = lane >> 4;
    const int m0 = blockIdx.x * 64 + w * 16;
    const int cb = blockIdx.y * 64;

    f32x4 acc[4] = {};
    const ushort_t* Ap = A + (size_t)(m0 + l16) * K + 8 * g;
    const ushort_t* Bp = Bt + (size_t)(cb + l16) * K + 8 * g;
    #pragma unroll
    for (int ks = 0; ks < K; ks += 32) {
        short8 a = *reinterpret_cast<const short8*>(Ap + ks);
        #pragma unroll
        for (int c = 0; c < 4; ++c) {
            short8 b = *reinterpret_cast<const short8*>(Bp + (size_t)c * 16 * K + ks);
            acc[c] = __builtin_amdgcn_mfma_f32_16x16x32_bf16(a, b, acc[c], 0, 0, 0);
        }
    }
    #pragma unroll
    for (int c = 0; c < 4; ++c) {
        int col = cb + c * 16 + l16;
        #pragma unroll
        for (int r = 0; r < 4; ++r) {
            int row = m0 + 4 * g + r;
            C[(size_t)row * N + col] = acc[c][r] + bias[col];
        }
    }
}

// ---------- launch ----------
extern "C" void kernel_launch(void* const* d_in, const int* in_sizes, int n_in,
                              void* d_out, int out_size, void* d_ws, size_t ws_size,
                              hipStream_t stream) {
    const float* x_sed     = (const float*)d_in[0];
    const float* x_doa     = (const float*)d_in[1];
    const float* W_sed_in  = (const float*)d_in[2];
    const float* W_doa_in  = (const float*)d_in[3];
    const float* W_sed_out = (const float*)d_in[4];
    const float* b_sed_out = (const float*)d_in[5];
    const float* W_doa_out = (const float*)d_in[6];
    const float* b_doa_out = (const float*)d_in[7];
    float* out = (float*)d_out;

    ushort_t* ws = (ushort_t*)d_ws;
    ushort_t* wt_si  = ws;                          // 512*256
    ushort_t* wt_di  = wt_si  + 131072;             // 512*256
    ushort_t* wt_so  = wt_di  + 131072;             // 256*256
    ushort_t* wt_do  = wt_so  + 65536;              // 256*256
    ushort_t* rH_sed = wt_do  + 65536;              // 16*2048*32
    ushort_t* rH_doa = rH_sed + 1048576;
    ushort_t* vT_sed = rH_doa + 1048576;            // 16*32*2048
    ushort_t* vT_doa = vT_sed + 1048576;
    ushort_t* o_sed  = vT_doa + 1048576;            // 4096*256
    ushort_t* o_doa  = o_sed  + 1048576;
    // total ~13.3 MB of ws

    prep_w_kernel<<<dim3(512, 4), 256, 0, stream>>>(W_sed_in, W_doa_in, W_sed_out, W_doa_out,
                                                    wt_si, wt_di, wt_so, wt_do);
    gemm_in_kernel<<<dim3(64, 8, 2), 256, 0, stream>>>(x_sed, x_doa, wt_si, wt_di,
                                                       rH_sed, rH_doa, vT_sed, vT_doa);
    attn_kernel<<<dim3(32, 16, 2), 256, 0, stream>>>(rH_sed, rH_doa, vT_sed, vT_doa, o_sed, o_doa);
    gemm_out_kernel<<<dim3(64, 4, 2), 256, 0, stream>>>(o_sed, o_doa, wt_so, wt_do,
                                                        out, out + 1048576, b_sed_out, b_doa_out);
}

// Round 3
// 119.243 us; speedup vs baseline: 1.5780x; 1.5780x over previous
//
#include <hip/hip_runtime.h>
#include <hip/hip_bf16.h>

typedef short short8 __attribute__((ext_vector_type(8)));
typedef short short4v __attribute__((ext_vector_type(4)));
typedef float f32x4 __attribute__((ext_vector_type(4)));
typedef unsigned short ushort_t;

// ---------- bf16 helpers ----------
__device__ inline ushort_t f2bf(float f) {            // manual RNE (cold paths)
    union { float f; unsigned u; } x; x.f = f;
    unsigned r = x.u + 0x7fffu + ((x.u >> 16) & 1u);
    return (ushort_t)(r >> 16);
}
__device__ inline ushort_t f2bf_u(float x) {           // toolchain conversion (hot paths)
    union { __hip_bfloat16 h; ushort_t u; } cv;
    cv.h = __float2bfloat16(x);
    return cv.u;
}
__device__ inline float bf2f(ushort_t u) {
    union { unsigned u; float f; } cv; cv.u = ((unsigned)u) << 16; return cv.f;
}

// ---------- transpose + convert weights: Wt[j][k] = bf16(W[k][j]), K=256 rows ----------
__global__ __launch_bounds__(256) void prep_w_kernel(const float* __restrict__ w0,
                                                     const float* __restrict__ w1,
                                                     const float* __restrict__ w2,
                                                     const float* __restrict__ w3,
                                                     ushort_t* __restrict__ t0,
                                                     ushort_t* __restrict__ t1,
                                                     ushort_t* __restrict__ t2,
                                                     ushort_t* __restrict__ t3) {
    int z = blockIdx.y;
    const float* W; ushort_t* T; int J;
    if (z == 0)      { W = w0; T = t0; J = 512; }
    else if (z == 1) { W = w1; T = t1; J = 512; }
    else if (z == 2) { W = w2; T = t2; J = 256; }
    else             { W = w3; T = t3; J = 256; }
    int idx = blockIdx.x * 256 + threadIdx.x;   // idx = j*256 + k
    if (idx >= J * 256) return;
    int k = idx & 255, j = idx >> 8;
    T[idx] = f2bf(W[k * J + j]);
}

// ---------- in-projection GEMM (fused f32->bf16 convert of A) ----------
__global__ __launch_bounds__(256) void gemm_in_kernel(
    const float* __restrict__ A0, const float* __restrict__ A1,
    const ushort_t* __restrict__ B0, const ushort_t* __restrict__ B1,
    ushort_t* __restrict__ R0, ushort_t* __restrict__ R1,
    ushort_t* __restrict__ V0, ushort_t* __restrict__ V1) {
    const float* A = blockIdx.z ? A1 : A0;
    const ushort_t* Bt = blockIdx.z ? B1 : B0;
    ushort_t* R = blockIdx.z ? R1 : R0;
    ushort_t* Vt = blockIdx.z ? V1 : V0;
    constexpr int K = 256;
    const int w = threadIdx.x >> 6, lane = threadIdx.x & 63;
    const int l16 = lane & 15, g = lane >> 4;
    const int m0 = blockIdx.x * 64 + w * 16;
    const int cb = blockIdx.y * 64;

    f32x4 acc[4] = {};
    const float* Ap = A + (size_t)(m0 + l16) * K + 8 * g;
    const ushort_t* Bp = Bt + (size_t)(cb + l16) * K + 8 * g;

    #pragma unroll
    for (int ks = 0; ks < K; ks += 32) {
        float4 af0 = *reinterpret_cast<const float4*>(Ap + ks);
        float4 af1 = *reinterpret_cast<const float4*>(Ap + ks + 4);
        short8 a;
        a[0] = (short)f2bf_u(af0.x); a[1] = (short)f2bf_u(af0.y);
        a[2] = (short)f2bf_u(af0.z); a[3] = (short)f2bf_u(af0.w);
        a[4] = (short)f2bf_u(af1.x); a[5] = (short)f2bf_u(af1.y);
        a[6] = (short)f2bf_u(af1.z); a[7] = (short)f2bf_u(af1.w);
        #pragma unroll
        for (int c = 0; c < 4; ++c) {
            short8 b = *reinterpret_cast<const short8*>(Bp + (size_t)c * 16 * K + ks);
            acc[c] = __builtin_amdgcn_mfma_f32_16x16x32_bf16(a, b, acc[c], 0, 0, 0);
        }
    }

    if (blockIdx.y < 4) {
        #pragma unroll
        for (int c = 0; c < 4; ++c) {
            int col = cb + c * 16 + l16;        // 0..255
            int h = col >> 5, d = col & 31;
            #pragma unroll
            for (int r = 0; r < 4; ++r) {
                int row = m0 + 4 * g + r;
                int bb = row >> 11, n = row & 2047;
                R[((size_t)(bb * 8 + h) * 2048 + n) * 32 + d] = f2bf_u(acc[c][r]);
            }
        }
    } else {
        #pragma unroll
        for (int c = 0; c < 4; ++c) {
            int colp = cb - 256 + c * 16 + l16; // 0..255
            int h = colp >> 5, d = colp & 31;
            int row = m0 + 4 * g;
            int bb = row >> 11, n = row & 2047;
            ushort4 s;
            s.x = f2bf_u(acc[c][0]); s.y = f2bf_u(acc[c][1]);
            s.z = f2bf_u(acc[c][2]); s.w = f2bf_u(acc[c][3]);
            *reinterpret_cast<ushort4*>(Vt + ((size_t)(bb * 8 + h) * 32 + d) * 2048 + n) = s;
        }
    }
}

// ---------- flash attention, both directions, no LDS ----------
// rH: [16][2048][32] bf16. vT: [16][32][2048] bf16. O: [B][N][256] bf16.
// 1-D grid of 512 blocks, XCD-swizzled: each XCD owns 4 complete (bh,dir) K/V
// streams (1 MB) so K/V loads hit its private L2. Each wave: 32 q-rows
// (2 fragments), double-buffered K/V prefetch, deferred-max softmax.
__global__ __launch_bounds__(256, 2) void attn_kernel(
    const ushort_t* __restrict__ r_sed, const ushort_t* __restrict__ r_doa,
    const ushort_t* __restrict__ vT_sed, const ushort_t* __restrict__ vT_doa,
    ushort_t* __restrict__ o_sed, ushort_t* __restrict__ o_doa) {
    const int flat = blockIdx.x;           // 0..511
    const int xcd = flat & 7;
    const int ii = flat >> 3;              // 0..63
    const int yz = xcd * 4 + (ii & 3);     // 0..31: (dir,bh) stream id
    const int xb = ii >> 2;                // 0..15: q-tile
    const int dir = yz >> 4;
    const int bh = yz & 15;
    const int b = bh >> 3, h = bh & 7;

    const ushort_t* rQ = dir ? r_doa : r_sed;
    const ushort_t* rK = dir ? r_sed : r_doa;
    const ushort_t* vT = dir ? vT_sed : vT_doa;
    ushort_t* O = dir ? o_doa : o_sed;

    const int w = threadIdx.x >> 6;
    const int lane = threadIdx.x & 63;
    const int l16 = lane & 15, g = lane >> 4;
    const int qbase = xb * 128 + w * 32;

    // Q fragments, pre-scaled by SCALE*log2(e)
    const float C2 = 0.17677669529663687f * 1.4426950408889634f;
    short8 qa, qb;
    {
        short8 q0 = *reinterpret_cast<const short8*>(rQ + ((size_t)bh * 2048 + qbase + l16) * 32 + 8 * g);
        short8 q1 = *reinterpret_cast<const short8*>(rQ + ((size_t)bh * 2048 + qbase + 16 + l16) * 32 + 8 * g);
        #pragma unroll
        for (int i = 0; i < 8; ++i) {
            qa[i] = (short)f2bf(bf2f((ushort_t)q0[i]) * C2);
            qb[i] = (short)f2bf(bf2f((ushort_t)q1[i]) * C2);
        }
    }

    const ushort_t* Kb = rK + (size_t)bh * 2048 * 32 + 8 * g;
    const ushort_t* Vp0 = vT + ((size_t)bh * 32 + l16) * 2048 + 4 * g;   // d = l16
    const ushort_t* Vp1 = Vp0 + (size_t)16 * 2048;                       // d = l16+16

    float ma = -1e30f, m8a = -1e30f, mb = -1e30f, m8b = -1e30f;
    f32x4 lva = {}, lvb = {};
    f32x4 aa0 = {}, aa1 = {}, ab0 = {}, ab1 = {};

    auto loadK = [&](int kv0, short8& k0, short8& k1) {
        k0 = *reinterpret_cast<const short8*>(Kb + (size_t)(kv0 + l16) * 32);
        k1 = *reinterpret_cast<const short8*>(Kb + (size_t)(kv0 + 16 + l16) * 32);
    };
    auto loadV = [&](int kv0, short8& f0, short8& f1) {
        short4v a0 = *reinterpret_cast<const short4v*>(Vp0 + kv0);
        short4v a1 = *reinterpret_cast<const short4v*>(Vp0 + kv0 + 16);
        short4v c0 = *reinterpret_cast<const short4v*>(Vp1 + kv0);
        short4v c1 = *reinterpret_cast<const short4v*>(Vp1 + kv0 + 16);
        f0 = __builtin_shufflevector(a0, a1, 0, 1, 2, 3, 4, 5, 6, 7);
        f1 = __builtin_shufflevector(c0, c1, 0, 1, 2, 3, 4, 5, 6, 7);
    };

    auto step = [&](short8 kf0, short8 kf1, short8 vf0, short8 vf1) {
        const f32x4 z4 = {};
        f32x4 sa0 = __builtin_amdgcn_mfma_f32_16x16x32_bf16(kf0, qa, z4, 0, 0, 0);
        f32x4 sa1 = __builtin_amdgcn_mfma_f32_16x16x32_bf16(kf1, qa, z4, 0, 0, 0);
        f32x4 sb0 = __builtin_amdgcn_mfma_f32_16x16x32_bf16(kf0, qb, z4, 0, 0, 0);
        f32x4 sb1 = __builtin_amdgcn_mfma_f32_16x16x32_bf16(kf1, qb, z4, 0, 0, 0);

        float pma = fmaxf(fmaxf(fmaxf(sa0[0], sa0[1]), fmaxf(sa0[2], sa0[3])),
                          fmaxf(fmaxf(sa1[0], sa1[1]), fmaxf(sa1[2], sa1[3])));
        float pmb = fmaxf(fmaxf(fmaxf(sb0[0], sb0[1]), fmaxf(sb0[2], sb0[3])),
                          fmaxf(fmaxf(sb1[0], sb1[1]), fmaxf(sb1[2], sb1[3])));

        if (!__all((pma <= m8a) && (pmb <= m8b))) {   // deferred-max trigger (rare)
            float ra = fmaxf(pma, __shfl_xor(pma, 16));
            ra = fmaxf(ra, __shfl_xor(ra, 32));
            float mna = fmaxf(ma, ra);
            float ala = __builtin_amdgcn_exp2f(ma - mna);
            lva *= ala; aa0 *= ala; aa1 *= ala;
            ma = mna; m8a = mna + 8.0f;

            float rb = fmaxf(pmb, __shfl_xor(pmb, 16));
            rb = fmaxf(rb, __shfl_xor(rb, 32));
            float mnb = fmaxf(mb, rb);
            float alb = __builtin_amdgcn_exp2f(mb - mnb);
            lvb *= alb; ab0 *= alb; ab1 *= alb;
            mb = mnb; m8b = mnb + 8.0f;
        }

        f32x4 pa0, pa1, pb0, pb1;
        #pragma unroll
        for (int r = 0; r < 4; ++r) {
            pa0[r] = __builtin_amdgcn_exp2f(sa0[r] - ma);
            pa1[r] = __builtin_amdgcn_exp2f(sa1[r] - ma);
            pb0[r] = __builtin_amdgcn_exp2f(sb0[r] - mb);
            pb1[r] = __builtin_amdgcn_exp2f(sb1[r] - mb);
        }
        lva += pa0; lva += pa1;
        lvb += pb0; lvb += pb1;

        short8 pfa, pfb;
        #pragma unroll
        for (int r = 0; r < 4; ++r) {
            pfa[r] = (short)f2bf_u(pa0[r]); pfa[4 + r] = (short)f2bf_u(pa1[r]);
            pfb[r] = (short)f2bf_u(pb0[r]); pfb[4 + r] = (short)f2bf_u(pb1[r]);
        }

        aa0 = __builtin_amdgcn_mfma_f32_16x16x32_bf16(vf0, pfa, aa0, 0, 0, 0);
        aa1 = __builtin_amdgcn_mfma_f32_16x16x32_bf16(vf1, pfa, aa1, 0, 0, 0);
        ab0 = __builtin_amdgcn_mfma_f32_16x16x32_bf16(vf0, pfb, ab0, 0, 0, 0);
        ab1 = __builtin_amdgcn_mfma_f32_16x16x32_bf16(vf1, pfb, ab1, 0, 0, 0);
    };

    short8 kA0, kA1, vA0, vA1, kB0, kB1, vB0, vB1;
    loadK(0, kA0, kA1); loadV(0, vA0, vA1);
    for (int kv0 = 0; kv0 < 2048; kv0 += 64) {
        loadK(kv0 + 32, kB0, kB1); loadV(kv0 + 32, vB0, vB1);
        step(kA0, kA1, vA0, vA1);
        if (kv0 + 64 < 2048) { loadK(kv0 + 64, kA0, kA1); loadV(kv0 + 64, vA0, vA1); }
        step(kB0, kB1, vB0, vB1);
    }

    float la = (lva[0] + lva[1]) + (lva[2] + lva[3]);
    la += __shfl_xor(la, 16); la += __shfl_xor(la, 32);
    float lb = (lvb[0] + lvb[1]) + (lvb[2] + lvb[3]);
    lb += __shfl_xor(lb, 16); lb += __shfl_xor(lb, 32);
    const float inva = 1.0f / la, invb = 1.0f / lb;

    ushort_t* orA = O + ((size_t)b * 2048 + qbase + l16) * 256 + h * 32;
    ushort_t* orB = O + ((size_t)b * 2048 + qbase + 16 + l16) * 256 + h * 32;
    ushort4 o0, o1;
    o0.x = f2bf(aa0[0] * inva); o0.y = f2bf(aa0[1] * inva);
    o0.z = f2bf(aa0[2] * inva); o0.w = f2bf(aa0[3] * inva);
    o1.x = f2bf(aa1[0] * inva); o1.y = f2bf(aa1[1] * inva);
    o1.z = f2bf(aa1[2] * inva); o1.w = f2bf(aa1[3] * inva);
    *reinterpret_cast<ushort4*>(orA + 4 * g) = o0;
    *reinterpret_cast<ushort4*>(orA + 16 + 4 * g) = o1;
    o0.x = f2bf(ab0[0] * invb); o0.y = f2bf(ab0[1] * invb);
    o0.z = f2bf(ab0[2] * invb); o0.w = f2bf(ab0[3] * invb);
    o1.x = f2bf(ab1[0] * invb); o1.y = f2bf(ab1[1] * invb);
    o1.z = f2bf(ab1[2] * invb); o1.w = f2bf(ab1[3] * invb);
    *reinterpret_cast<ushort4*>(orB + 4 * g) = o0;
    *reinterpret_cast<ushort4*>(orB + 16 + 4 * g) = o1;
}

// ---------- out-projection GEMM: C[4096 x 256] = A @ Bt^T + bias, f32 out ----------
__global__ __launch_bounds__(256) void gemm_out_kernel(
    const ushort_t* __restrict__ a0, const ushort_t* __restrict__ a1,
    const ushort_t* __restrict__ b0, const ushort_t* __restrict__ b1,
    float* __restrict__ c0, float* __restrict__ c1,
    const float* __restrict__ bias0, const float* __restrict__ bias1) {
    const ushort_t* A = blockIdx.z ? a1 : a0;
    const ushort_t* Bt = blockIdx.z ? b1 : b0;
    float* C = blockIdx.z ? c1 : c0;
    const float* bias = blockIdx.z ? bias1 : bias0;
    constexpr int K = 256, N = 256;
    const int w = threadIdx.x >> 6, lane = threadIdx.x & 63;
    const int l16 = lane & 15, g = lane >> 4;
    const int m0 = blockIdx.x * 64 + w * 16;
    const int cb = blockIdx.y * 64;

    f32x4 acc[4] = {};
    const ushort_t* Ap = A + (size_t)(m0 + l16) * K + 8 * g;
    const ushort_t* Bp = Bt + (size_t)(cb + l16) * K + 8 * g;
    #pragma unroll
    for (int ks = 0; ks < K; ks += 32) {
        short8 a = *reinterpret_cast<const short8*>(Ap + ks);
        #pragma unroll
        for (int c = 0; c < 4; ++c) {
            short8 b = *reinterpret_cast<const short8*>(Bp + (size_t)c * 16 * K + ks);
            acc[c] = __builtin_amdgcn_mfma_f32_16x16x32_bf16(a, b, acc[c], 0, 0, 0);
        }
    }
    #pragma unroll
    for (int c = 0; c < 4; ++c) {
        int col = cb + c * 16 + l16;
        #pragma unroll
        for (int r = 0; r < 4; ++r) {
            int row = m0 + 4 * g + r;
            C[(size_t)row * N + col] = acc[c][r] + bias[col];
        }
    }
}

// ---------- launch ----------
extern "C" void kernel_launch(void* const* d_in, const int* in_sizes, int n_in,
                              void* d_out, int out_size, void* d_ws, size_t ws_size,
                              hipStream_t stream) {
    const float* x_sed     = (const float*)d_in[0];
    const float* x_doa     = (const float*)d_in[1];
    const float* W_sed_in  = (const float*)d_in[2];
    const float* W_doa_in  = (const float*)d_in[3];
    const float* W_sed_out = (const float*)d_in[4];
    const float* b_sed_out = (const float*)d_in[5];
    const float* W_doa_out = (const float*)d_in[6];
    const float* b_doa_out = (const float*)d_in[7];
    float* out = (float*)d_out;

    ushort_t* ws = (ushort_t*)d_ws;
    ushort_t* wt_si  = ws;                          // 512*256
    ushort_t* wt_di  = wt_si  + 131072;             // 512*256
    ushort_t* wt_so  = wt_di  + 131072;             // 256*256
    ushort_t* wt_do  = wt_so  + 65536;              // 256*256
    ushort_t* rH_sed = wt_do  + 65536;              // 16*2048*32
    ushort_t* rH_doa = rH_sed + 1048576;
    ushort_t* vT_sed = rH_doa + 1048576;            // 16*32*2048
    ushort_t* vT_doa = vT_sed + 1048576;
    ushort_t* o_sed  = vT_doa + 1048576;            // 4096*256
    ushort_t* o_doa  = o_sed  + 1048576;
    // total ~13.3 MB of ws

    prep_w_kernel<<<dim3(512, 4), 256, 0, stream>>>(W_sed_in, W_doa_in, W_sed_out, W_doa_out,
                                                    wt_si, wt_di, wt_so, wt_do);
    gemm_in_kernel<<<dim3(64, 8, 2), 256, 0, stream>>>(x_sed, x_doa, wt_si, wt_di,
                                                       rH_sed, rH_doa, vT_sed, vT_doa);
    attn_kernel<<<dim3(512), 256, 0, stream>>>(rH_sed, rH_doa, vT_sed, vT_doa, o_sed, o_doa);
    gemm_out_kernel<<<dim3(64, 4, 2), 256, 0, stream>>>(o_sed, o_doa, wt_so, wt_do,
                                                        out, out + 1048576, b_sed_out, b_doa_out);
}